// Round 4
// baseline (271.664 us; speedup 1.0000x reference)
//
#include <hip/hip_runtime.h>

// EdgeLoss: loss = mean|Sobel_x(d)| + mean|Sobel_y(d)|, d = gray(sr) - gray(hr)
// B=32, C=3, H=W=512. 201 MB mandatory read.
// R2 lesson: fused strip kernel flat at 79 us across occupancy 33->53% ->
// throughput wall, not latency. This round: two-pass split (R3 = syntax fix).
//   Pass1 (copy-shaped streaming): d = gray-diff -> d_ws (33.5 MB).
//   Pass2 (register+shfl Sobel, no LDS): read d, reduce |gx|+|gy|.

// ---------------- Pass 1: gray-diff, pure streaming ----------------
// 1024 blocks x 256 thr; each thread 8 float4 groups in 2 batches of 4
// (24 independent loads in flight per batch).
__global__ __launch_bounds__(256, 4)
void gray_diff_kernel(const float* __restrict__ sr, const float* __restrict__ hr,
                      float* __restrict__ dd) {
    const int t = blockIdx.x * 256 + threadIdx.x;   // 0..262143
    #pragma unroll
    for (int half = 0; half < 2; ++half) {
        float4 sR[4], sG[4], sB[4], hR[4], hG[4], hB[4];
        #pragma unroll
        for (int k = 0; k < 4; ++k) {
            const int p   = t + (half * 4 + k) * 262144;  // float4 idx in gray vol
            const int img = p >> 16;                       // 65536 groups per image
            const int g   = p & 65535;
            const size_t base = (size_t)img * 786432 + ((size_t)g << 2);
            sR[k] = *(const float4*)(sr + base);
            sG[k] = *(const float4*)(sr + base + 262144);
            sB[k] = *(const float4*)(sr + base + 524288);
            hR[k] = *(const float4*)(hr + base);
            hG[k] = *(const float4*)(hr + base + 262144);
            hB[k] = *(const float4*)(hr + base + 524288);
        }
        #pragma unroll
        for (int k = 0; k < 4; ++k) {
            const int p = t + (half * 4 + k) * 262144;
            float4 o;
            o.x = 0.2989f*(sR[k].x-hR[k].x) + 0.587f*(sG[k].x-hG[k].x) + 0.114f*(sB[k].x-hB[k].x);
            o.y = 0.2989f*(sR[k].y-hR[k].y) + 0.587f*(sG[k].y-hG[k].y) + 0.114f*(sB[k].y-hB[k].y);
            o.z = 0.2989f*(sR[k].z-hR[k].z) + 0.587f*(sG[k].z-hG[k].z) + 0.114f*(sB[k].z-hB[k].z);
            o.w = 0.2989f*(sR[k].w-hR[k].w) + 0.587f*(sG[k].w-hG[k].w) + 0.114f*(sB[k].w-hB[k].w);
            *(float4*)(dd + ((size_t)p << 2)) = o;
        }
    }
}

// ---------------- Pass 2: Sobel + reduce, register/shfl ----------------
// One wave per image row (512 px, 8 px/lane). Block = 4 waves = 4 consecutive
// rows (L1 vertical reuse). 32 imgs x 128 row-groups = 4096 blocks.
__global__ __launch_bounds__(256, 8)
void sobel_sum_kernel(const float* __restrict__ dd, float* __restrict__ out) {
    const int tid  = threadIdx.x;
    const int lane = tid & 63;
    const int w    = tid >> 6;
    const int img  = blockIdx.x >> 7;
    const int rg   = blockIdx.x & 127;
    const int y    = rg * 4 + w;                 // 0..511, wave-uniform
    const float* base = dd + (size_t)img * 262144;
    const int c0 = lane << 3;                    // 8 px per lane

    float dm[8], dc[8], dp[8];
    {   // center row
        const float4 a = *(const float4*)(base + y * 512 + c0);
        const float4 b = *(const float4*)(base + y * 512 + c0 + 4);
        dc[0]=a.x; dc[1]=a.y; dc[2]=a.z; dc[3]=a.w; dc[4]=b.x; dc[5]=b.y; dc[6]=b.z; dc[7]=b.w;
    }
    if (y > 0) {   // row above (wave-uniform branch)
        const float4 a = *(const float4*)(base + (y-1) * 512 + c0);
        const float4 b = *(const float4*)(base + (y-1) * 512 + c0 + 4);
        dm[0]=a.x; dm[1]=a.y; dm[2]=a.z; dm[3]=a.w; dm[4]=b.x; dm[5]=b.y; dm[6]=b.z; dm[7]=b.w;
    } else {
        #pragma unroll
        for (int j = 0; j < 8; ++j) dm[j] = 0.f;
    }
    if (y < 511) { // row below
        const float4 a = *(const float4*)(base + (y+1) * 512 + c0);
        const float4 b = *(const float4*)(base + (y+1) * 512 + c0 + 4);
        dp[0]=a.x; dp[1]=a.y; dp[2]=a.z; dp[3]=a.w; dp[4]=b.x; dp[5]=b.y; dp[6]=b.z; dp[7]=b.w;
    } else {
        #pragma unroll
        for (int j = 0; j < 8; ++j) dp[j] = 0.f;
    }

    float s[8], u[8];
    #pragma unroll
    for (int j = 0; j < 8; ++j) {
        s[j] = dm[j] + 2.f * dc[j] + dp[j];   // vertical [1,2,1]
        u[j] = dm[j] - dp[j];                 // vertical [1,0,-1]
    }
    // horizontal halo via cross-lane shfl (lane i-1's px7 = col 8i-1, etc.)
    float sL = __shfl_up(s[7], 1, 64);   if (lane == 0)  sL = 0.f;  // SAME pad
    float sR = __shfl_down(s[0], 1, 64); if (lane == 63) sR = 0.f;
    float uL = __shfl_up(u[7], 1, 64);   if (lane == 0)  uL = 0.f;
    float uR = __shfl_down(u[0], 1, 64); if (lane == 63) uR = 0.f;

    float acc = 0.f;
    acc += fabsf(sL - s[1]);                       // gx, j=0
    #pragma unroll
    for (int j = 1; j < 7; ++j) acc += fabsf(s[j-1] - s[j+1]);
    acc += fabsf(s[6] - sR);                       // gx, j=7
    acc += fabsf(uL + 2.f*u[0] + u[1]);            // gy, j=0 (sign moot under abs)
    #pragma unroll
    for (int j = 1; j < 7; ++j) acc += fabsf(u[j-1] + 2.f*u[j] + u[j+1]);
    acc += fabsf(u[6] + 2.f*u[7] + uR);            // gy, j=7

    #pragma unroll
    for (int o = 32; o > 0; o >>= 1) acc += __shfl_down(acc, o, 64);
    __shared__ float wsum[4];
    if (lane == 0) wsum[w] = acc;
    __syncthreads();
    if (tid == 0)
        atomicAdd(out, (wsum[0] + wsum[1] + wsum[2] + wsum[3]) * (1.0f / 8388608.0f));
}

// ---------------- Fallback: R2 fused kernel (if ws too small) ----------------
#define TH 8
#define TILE_ROWS (TH + 2)
#define ROWSTRIDE 516

__global__ __launch_bounds__(256, 8)
void edge_loss_fused(const float* __restrict__ sr, const float* __restrict__ hr,
                     float* __restrict__ out) {
    __shared__ float tile[TILE_ROWS][ROWSTRIDE];
    const int tid   = threadIdx.x;
    const int img   = blockIdx.x >> 6;
    const int strip = blockIdx.x & 63;
    const int row0  = strip * TH;
    if (tid < TILE_ROWS) { tile[tid][0] = 0.f; tile[tid][513] = 0.f; }
    const size_t imgBase = (size_t)img * (3 * 512 * 512);
    const float* __restrict__ srp = sr + imgBase;
    const float* __restrict__ hrp = hr + imgBase;
    for (int idx = tid; idx < TILE_ROWS * 128; idx += 256) {
        const int r  = idx >> 7;
        const int x4 = (idx & 127) << 2;
        const int gr = row0 - 1 + r;
        float dx = 0.f, dy = 0.f, dz = 0.f, dw = 0.f;
        if (gr >= 0 && gr < 512) {
            const size_t off = (size_t)gr * 512 + x4;
            const float4 sR = *(const float4*)(srp + off);
            const float4 sG = *(const float4*)(srp + off + 262144);
            const float4 sB = *(const float4*)(srp + off + 524288);
            const float4 hR = *(const float4*)(hrp + off);
            const float4 hG = *(const float4*)(hrp + off + 262144);
            const float4 hB = *(const float4*)(hrp + off + 524288);
            dx = 0.2989f*(sR.x-hR.x) + 0.587f*(sG.x-hG.x) + 0.114f*(sB.x-hB.x);
            dy = 0.2989f*(sR.y-hR.y) + 0.587f*(sG.y-hG.y) + 0.114f*(sB.y-hB.y);
            dz = 0.2989f*(sR.z-hR.z) + 0.587f*(sG.z-hG.z) + 0.114f*(sB.z-hB.z);
            dw = 0.2989f*(sR.w-hR.w) + 0.587f*(sG.w-hG.w) + 0.114f*(sB.w-hB.w);
        }
        float* t = &tile[r][1 + x4];
        t[0] = dx; t[1] = dy; t[2] = dz; t[3] = dw;
    }
    __syncthreads();
    float acc = 0.f;
    #pragma unroll
    for (int i = 0; i < 4; ++i) {
        const int g  = tid + (i << 8);
        const int r  = g >> 7;
        const int x4 = (g & 127) << 2;
        const float* A  = &tile[r][x4];
        const float* Bc = &tile[r + 1][x4];
        const float* Cc = &tile[r + 2][x4];
        const float a0=A[0],a1=A[1],a2=A[2],a3=A[3],a4=A[4],a5=A[5];
        const float b0=Bc[0],b1=Bc[1],b2=Bc[2],b3=Bc[3],b4=Bc[4],b5=Bc[5];
        const float c0=Cc[0],c1=Cc[1],c2=Cc[2],c3=Cc[3],c4=Cc[4],c5=Cc[5];
        const float s0=a0+2.f*b0+c0, s1=a1+2.f*b1+c1, s2=a2+2.f*b2+c2,
                    s3=a3+2.f*b3+c3, s4=a4+2.f*b4+c4, s5=a5+2.f*b5+c5;
        acc += fabsf(s0 - s2) + fabsf(s1 - s3) + fabsf(s2 - s4) + fabsf(s3 - s5);
        acc += fabsf((a0 + 2.f*a1 + a2) - (c0 + 2.f*c1 + c2));
        acc += fabsf((a1 + 2.f*a2 + a3) - (c1 + 2.f*c2 + c3));
        acc += fabsf((a2 + 2.f*a3 + a4) - (c2 + 2.f*c3 + c4));
        acc += fabsf((a3 + 2.f*a4 + a5) - (c3 + 2.f*c4 + c5));
    }
    #pragma unroll
    for (int o = 32; o > 0; o >>= 1) acc += __shfl_down(acc, o, 64);
    __shared__ float wsum[4];
    if ((tid & 63) == 0) wsum[tid >> 6] = acc;
    __syncthreads();
    if (tid == 0) {
        const float s = (wsum[0] + wsum[1] + wsum[2] + wsum[3]) * (1.0f / 8388608.0f);
        atomicAdd(out, s);
    }
}

extern "C" void kernel_launch(void* const* d_in, const int* in_sizes, int n_in,
                              void* d_out, int out_size, void* d_ws, size_t ws_size,
                              hipStream_t stream) {
    const float* sr = (const float*)d_in[0];
    const float* hr = (const float*)d_in[1];
    float* out = (float*)d_out;
    (void)hipMemsetAsync(out, 0, sizeof(float), stream);
    const size_t needed = (size_t)32 * 512 * 512 * 4;   // 33.5 MB for gray-diff
    if (ws_size >= needed) {
        float* dd = (float*)d_ws;
        gray_diff_kernel<<<dim3(1024), dim3(256), 0, stream>>>(sr, hr, dd);
        sobel_sum_kernel<<<dim3(4096), dim3(256), 0, stream>>>(dd, out);
    } else {
        edge_loss_fused<<<dim3(32 * 64), dim3(256), 0, stream>>>(sr, hr, out);
    }
}

// Round 6
// 210.282 us; speedup vs baseline: 1.2919x; 1.2919x over previous
//
#include <hip/hip_runtime.h>

// EdgeLoss: loss = mean|Sobel_x(d)| + mean|Sobel_y(d)|, d = gray(sr) - gray(hr)
// B=32, C=3, H=W=512. 201 MB mandatory read.
// R4 lesson: pure streaming kernel == fused kernel == 79 us (2.97 TB/s
// combined) while the harness's own D2D restore hits ~6 TB/s -> request-path
// wall, not platform. HBM 1.24 TB/s and LLC 1.3 TB/s BOTH under-used ->
// suspect cache-allocation path serialization. R6 = R5 retry with native
// clang vector type (HIP float4 is a class; builtin rejects it).

typedef float floatx4 __attribute__((ext_vector_type(4)));

#define TH 8                  // output rows per block
#define TILE_ROWS (TH + 2)    // +2 halo rows
#define ROWSTRIDE 516         // 512 + 2 pad cols + 2 align (rows 16B-aligned)

__global__ __launch_bounds__(256, 8)
void edge_loss_fused(const float* __restrict__ sr, const float* __restrict__ hr,
                     float* __restrict__ out) {
    __shared__ float tile[TILE_ROWS][ROWSTRIDE];
    const int tid = threadIdx.x;
    // XCD-contiguous swizzle: XCD x (= blockIdx%8) owns strips [x*256, x*256+256)
    // so vertically-adjacent strips (shared 2-row halo) stay in one XCD's L2.
    const int gs    = (blockIdx.x & 7) * 256 + (blockIdx.x >> 3);  // 0..2047
    const int img   = gs >> 6;
    const int strip = gs & 63;
    const int row0  = strip * TH;

    if (tid < TILE_ROWS) { tile[tid][0] = 0.f; tile[tid][513] = 0.f; }

    const size_t imgBase = (size_t)img * (3 * 512 * 512);
    const float* __restrict__ srp = sr + imgBase;
    const float* __restrict__ hrp = hr + imgBase;

    // Stage gray-diff tile: 10 rows x 512 cols, 16B/lane, coalesced.
    // Non-temporal: streaming data, zero intra-kernel reuse -> skip cache alloc.
    for (int idx = tid; idx < TILE_ROWS * 128; idx += 256) {
        const int r  = idx >> 7;
        const int x4 = (idx & 127) << 2;
        const int gr = row0 - 1 + r;
        float dx = 0.f, dy = 0.f, dz = 0.f, dw = 0.f;
        if (gr >= 0 && gr < 512) {
            const size_t off = (size_t)gr * 512 + x4;
            const floatx4 sR = __builtin_nontemporal_load((const floatx4*)(srp + off));
            const floatx4 sG = __builtin_nontemporal_load((const floatx4*)(srp + off + 262144));
            const floatx4 sB = __builtin_nontemporal_load((const floatx4*)(srp + off + 524288));
            const floatx4 hR = __builtin_nontemporal_load((const floatx4*)(hrp + off));
            const floatx4 hG = __builtin_nontemporal_load((const floatx4*)(hrp + off + 262144));
            const floatx4 hB = __builtin_nontemporal_load((const floatx4*)(hrp + off + 524288));
            dx = 0.2989f*(sR.x-hR.x) + 0.587f*(sG.x-hG.x) + 0.114f*(sB.x-hB.x);
            dy = 0.2989f*(sR.y-hR.y) + 0.587f*(sG.y-hG.y) + 0.114f*(sB.y-hB.y);
            dz = 0.2989f*(sR.z-hR.z) + 0.587f*(sG.z-hG.z) + 0.114f*(sB.z-hB.z);
            dw = 0.2989f*(sR.w-hR.w) + 0.587f*(sG.w-hG.w) + 0.114f*(sB.w-hB.w);
        }
        float* t = &tile[r][1 + x4];
        t[0] = dx; t[1] = dy; t[2] = dz; t[3] = dw;
    }
    __syncthreads();

    // 4 groups of 4 output pixels per thread: 8 rows x 128 groups.
    float acc = 0.f;
    #pragma unroll
    for (int i = 0; i < 4; ++i) {
        const int g  = tid + (i << 8);
        const int r  = g >> 7;
        const int x4 = (g & 127) << 2;
        const float* A  = &tile[r][x4];
        const float* Bc = &tile[r + 1][x4];
        const float* Cc = &tile[r + 2][x4];
        const float a0=A[0],a1=A[1],a2=A[2],a3=A[3],a4=A[4],a5=A[5];
        const float b0=Bc[0],b1=Bc[1],b2=Bc[2],b3=Bc[3],b4=Bc[4],b5=Bc[5];
        const float c0=Cc[0],c1=Cc[1],c2=Cc[2],c3=Cc[3],c4=Cc[4],c5=Cc[5];
        const float s0=a0+2.f*b0+c0, s1=a1+2.f*b1+c1, s2=a2+2.f*b2+c2,
                    s3=a3+2.f*b3+c3, s4=a4+2.f*b4+c4, s5=a5+2.f*b5+c5;
        acc += fabsf(s0 - s2) + fabsf(s1 - s3) + fabsf(s2 - s4) + fabsf(s3 - s5);
        acc += fabsf((a0 + 2.f*a1 + a2) - (c0 + 2.f*c1 + c2));
        acc += fabsf((a1 + 2.f*a2 + a3) - (c1 + 2.f*c2 + c3));
        acc += fabsf((a2 + 2.f*a3 + a4) - (c2 + 2.f*c3 + c4));
        acc += fabsf((a3 + 2.f*a4 + a5) - (c3 + 2.f*c4 + c5));
    }

    #pragma unroll
    for (int o = 32; o > 0; o >>= 1) acc += __shfl_down(acc, o, 64);
    __shared__ float wsum[4];
    if ((tid & 63) == 0) wsum[tid >> 6] = acc;
    __syncthreads();
    if (tid == 0) {
        const float s = (wsum[0] + wsum[1] + wsum[2] + wsum[3]) * (1.0f / 8388608.0f);
        atomicAdd(out, s);
    }
}

extern "C" void kernel_launch(void* const* d_in, const int* in_sizes, int n_in,
                              void* d_out, int out_size, void* d_ws, size_t ws_size,
                              hipStream_t stream) {
    const float* sr = (const float*)d_in[0];
    const float* hr = (const float*)d_in[1];
    float* out = (float*)d_out;
    (void)hipMemsetAsync(out, 0, sizeof(float), stream);
    edge_loss_fused<<<dim3(32 * 64), dim3(256), 0, stream>>>(sr, hr, out);
}

// Round 7
// 206.593 us; speedup vs baseline: 1.3150x; 1.0179x over previous
//
#include <hip/hip_runtime.h>

// EdgeLoss: loss = mean|Sobel_x(d)| + mean|Sobel_y(d)|, d = gray(sr) - gray(hr)
// B=32, C=3, H=W=512. 201 MB mandatory read.
// R6 lesson: NON-TEMPORAL loads broke the ~3 TB/s cache-path wall (kernel
// 79 -> <59 us, dropped out of rocprof top-5 behind the 59-61 us harness
// fills). New model: nt = HBM-direct, ~900 cyc; throughput = outstanding
// loads x 16B / 900 cyc -> MLP-bound. R7: hoist all 30 loads/thread
// (branch-free via row clamp + zero weight), (256,4) -> 128 VGPR cap,
// 16 waves/CU x ~24-30 in flight (vs ~300 total before).

typedef float floatx4 __attribute__((ext_vector_type(4)));

#define TH 8            // output rows per block
#define TILE_ROWS 10    // +2 halo rows
#define RS 520          // row stride (floats); data cols 4..515, zero pads 3 & 516

__global__ __launch_bounds__(256, 4)
void edge_loss_fused(const float* __restrict__ sr, const float* __restrict__ hr,
                     float* __restrict__ out) {
    __shared__ float tile[TILE_ROWS][RS];
    const int tid = threadIdx.x;
    // XCD-contiguous swizzle: adjacent strips (shared halo) on one XCD's L2.
    const int gs    = (blockIdx.x & 7) * 256 + (blockIdx.x >> 3);  // 0..2047
    const int img   = gs >> 6;
    const int strip = gs & 63;
    const int row0  = strip * TH;

    if (tid < TILE_ROWS) { tile[tid][3] = 0.f; tile[tid][516] = 0.f; }

    const size_t imgBase = (size_t)img * 786432;
    const float* __restrict__ s0p = sr + imgBase;
    const float* __restrict__ s1p = sr + imgBase + 262144;
    const float* __restrict__ s2p = sr + imgBase + 524288;
    const float* __restrict__ h0p = hr + imgBase;
    const float* __restrict__ h1p = hr + imgBase + 262144;
    const float* __restrict__ h2p = hr + imgBase + 524288;

    // Phase A: issue ALL 30 nt loads (no branches -> nothing blocks issue).
    floatx4 R0[5], G0[5], B0[5], R1[5], G1[5], B1[5];
    float wgt[5];
    #pragma unroll
    for (int i = 0; i < 5; ++i) {
        const int idx = tid + (i << 8);
        const int r   = idx >> 7;           // tile row 0..9
        const int x4  = (idx & 127) << 2;   // col 0,4,...,508
        const int gr  = row0 - 1 + r;       // global row (-1..512)
        const int grc = min(max(gr, 0), 511);
        wgt[i] = (gr == grc) ? 1.f : 0.f;   // zero out clamped halo rows
        const int off = grc * 512 + x4;
        R0[i] = __builtin_nontemporal_load((const floatx4*)(s0p + off));
        G0[i] = __builtin_nontemporal_load((const floatx4*)(s1p + off));
        B0[i] = __builtin_nontemporal_load((const floatx4*)(s2p + off));
        R1[i] = __builtin_nontemporal_load((const floatx4*)(h0p + off));
        G1[i] = __builtin_nontemporal_load((const floatx4*)(h1p + off));
        B1[i] = __builtin_nontemporal_load((const floatx4*)(h2p + off));
    }
    // Phase B: luma-diff + single 16B-aligned ds_write per group.
    #pragma unroll
    for (int i = 0; i < 5; ++i) {
        const int idx = tid + (i << 8);
        const int r   = idx >> 7;
        const int x4  = (idx & 127) << 2;
        floatx4 d;
        d.x = wgt[i] * (0.2989f*(R0[i].x-R1[i].x) + 0.587f*(G0[i].x-G1[i].x) + 0.114f*(B0[i].x-B1[i].x));
        d.y = wgt[i] * (0.2989f*(R0[i].y-R1[i].y) + 0.587f*(G0[i].y-G1[i].y) + 0.114f*(B0[i].y-B1[i].y));
        d.z = wgt[i] * (0.2989f*(R0[i].z-R1[i].z) + 0.587f*(G0[i].z-G1[i].z) + 0.114f*(B0[i].z-B1[i].z));
        d.w = wgt[i] * (0.2989f*(R0[i].w-R1[i].w) + 0.587f*(G0[i].w-G1[i].w) + 0.114f*(B0[i].w-B1[i].w));
        *(floatx4*)&tile[r][4 + x4] = d;    // (4+x4)*4B : 16B aligned
    }
    __syncthreads();

    // 4 groups of 4 output pixels per thread: 8 rows x 128 groups.
    // Output group base col x4 needs input cols x4-1..x4+4 = padded x4+3..x4+8.
    float acc = 0.f;
    #pragma unroll
    for (int i = 0; i < 4; ++i) {
        const int g  = tid + (i << 8);
        const int r  = g >> 7;
        const int x4 = (g & 127) << 2;
        const float* A  = &tile[r][x4 + 3];
        const float* Bc = &tile[r + 1][x4 + 3];
        const float* Cc = &tile[r + 2][x4 + 3];
        const float a0=A[0],a1=A[1],a2=A[2],a3=A[3],a4=A[4],a5=A[5];
        const float b0=Bc[0],b1=Bc[1],b2=Bc[2],b3=Bc[3],b4=Bc[4],b5=Bc[5];
        const float c0=Cc[0],c1=Cc[1],c2=Cc[2],c3=Cc[3],c4=Cc[4],c5=Cc[5];
        const float s0=a0+2.f*b0+c0, s1=a1+2.f*b1+c1, s2=a2+2.f*b2+c2,
                    s3=a3+2.f*b3+c3, s4=a4+2.f*b4+c4, s5=a5+2.f*b5+c5;
        acc += fabsf(s0 - s2) + fabsf(s1 - s3) + fabsf(s2 - s4) + fabsf(s3 - s5);
        acc += fabsf((a0 + 2.f*a1 + a2) - (c0 + 2.f*c1 + c2));
        acc += fabsf((a1 + 2.f*a2 + a3) - (c1 + 2.f*c2 + c3));
        acc += fabsf((a2 + 2.f*a3 + a4) - (c2 + 2.f*c3 + c4));
        acc += fabsf((a3 + 2.f*a4 + a5) - (c3 + 2.f*c4 + c5));
    }

    #pragma unroll
    for (int o = 32; o > 0; o >>= 1) acc += __shfl_down(acc, o, 64);
    __shared__ float wsum[4];
    if ((tid & 63) == 0) wsum[tid >> 6] = acc;
    __syncthreads();
    if (tid == 0) {
        const float s = (wsum[0] + wsum[1] + wsum[2] + wsum[3]) * (1.0f / 8388608.0f);
        atomicAdd(out, s);
    }
}

extern "C" void kernel_launch(void* const* d_in, const int* in_sizes, int n_in,
                              void* d_out, int out_size, void* d_ws, size_t ws_size,
                              hipStream_t stream) {
    const float* sr = (const float*)d_in[0];
    const float* hr = (const float*)d_in[1];
    float* out = (float*)d_out;
    (void)hipMemsetAsync(out, 0, sizeof(float), stream);
    edge_loss_fused<<<dim3(32 * 64), dim3(256), 0, stream>>>(sr, hr, out);
}